// Round 1
// baseline (704.292 us; speedup 1.0000x reference)
//
#include <hip/hip_runtime.h>
#include <hip/hip_bf16.h>
#include <stdint.h>

// Problem constants
#define N_ROWS 8192
#define IN_F   4096
#define OUT_F  4096
#define R_LORA 16
#define KP     4160   // padded K: 4096 data + col 4096 = bias-1.0 trick + zeros to /64

typedef __bf16 bf16_t;
typedef __attribute__((ext_vector_type(8))) __bf16 bf16x8;
typedef __attribute__((ext_vector_type(4))) __bf16 bf16x4;
typedef __attribute__((ext_vector_type(4))) float  f32x4;

// ---------------------------------------------------------------------------
// async global->LDS, 16B per lane. LDS dest must be wave_base + lane*16.
__device__ __forceinline__ void load16_lds(const bf16_t* g, bf16_t* l) {
    auto gp = (const __attribute__((address_space(1))) void*)g;
    auto lp = (__attribute__((address_space(3))) void*)(uint32_t)(uintptr_t)l;
    __builtin_amdgcn_global_load_lds(gp, lp, 16, 0, 0);
}

// ---------------------------------------------------------------------------
// prep_a: Aw[row][0:4096] = bf16(x), Aw[row][4096] = 1.0, rest of pad = 0.
// Row-major, stride KP. Memory-bound.
__global__ void prep_a(const float* __restrict__ x, bf16_t* __restrict__ Aw) {
    const int SLOTS_PER_ROW = KP / 8;           // 520 slots of 8 bf16
    const int total = N_ROWS * SLOTS_PER_ROW;
    for (int s = blockIdx.x * blockDim.x + threadIdx.x; s < total;
         s += gridDim.x * blockDim.x) {
        int row = s / SLOTS_PER_ROW;
        int c8  = (s - row * SLOTS_PER_ROW) * 8;
        bf16x8 v;
        if (c8 < IN_F) {
            const float4* xp = (const float4*)(x + (size_t)row * IN_F + c8);
            float4 f0 = xp[0], f1 = xp[1];
            v[0] = (bf16_t)f0.x; v[1] = (bf16_t)f0.y;
            v[2] = (bf16_t)f0.z; v[3] = (bf16_t)f0.w;
            v[4] = (bf16_t)f1.x; v[5] = (bf16_t)f1.y;
            v[6] = (bf16_t)f1.z; v[7] = (bf16_t)f1.w;
        } else {
            for (int j = 0; j < 8; ++j) v[j] = (bf16_t)0.0f;
            if (c8 == IN_F) v[0] = (bf16_t)1.0f;   // bias column
        }
        *(bf16x8*)(Aw + (size_t)row * KP + c8) = v;
    }
}

// ---------------------------------------------------------------------------
// prep_b: Bw[o][i] = bf16( W[o][i] + 2*sum_r lora_B[o][r]*lora_A[r][i] ),
//         Bw[o][4096] = bf16(b[o]), rest of pad = 0.
// One block handles 4 consecutive o rows. lora_B reads are block-uniform.
__global__ void prep_b(const float* __restrict__ W, const float* __restrict__ bias,
                       const float* __restrict__ lA, const float* __restrict__ lB,
                       bf16_t* __restrict__ Bw) {
    int o0 = blockIdx.x * 4;
    int t  = threadIdx.x;

    float bl[4][R_LORA];
    for (int oo = 0; oo < 4; ++oo)
        for (int r = 0; r < R_LORA; ++r)
            bl[oo][r] = 2.0f * lB[(o0 + oo) * R_LORA + r];

    for (int j = 0; j < IN_F / (256 * 4); ++j) {   // 4 iterations
        int i4 = (j * 256 + t) * 4;
        f32x4 acc[4];
        for (int oo = 0; oo < 4; ++oo) {
            float4 w = *(const float4*)(W + (size_t)(o0 + oo) * IN_F + i4);
            acc[oo] = (f32x4){w.x, w.y, w.z, w.w};
        }
        for (int r = 0; r < R_LORA; ++r) {
            float4 a = *(const float4*)(lA + (size_t)r * IN_F + i4);
            for (int oo = 0; oo < 4; ++oo) {
                acc[oo][0] += bl[oo][r] * a.x;
                acc[oo][1] += bl[oo][r] * a.y;
                acc[oo][2] += bl[oo][r] * a.z;
                acc[oo][3] += bl[oo][r] * a.w;
            }
        }
        for (int oo = 0; oo < 4; ++oo) {
            bf16x4 v;
            v[0] = (bf16_t)acc[oo][0]; v[1] = (bf16_t)acc[oo][1];
            v[2] = (bf16_t)acc[oo][2]; v[3] = (bf16_t)acc[oo][3];
            *(bf16x4*)(Bw + (size_t)(o0 + oo) * KP + i4) = v;
        }
    }
    // pad columns: 4 rows x 64 cols = 256 slots, one per thread
    {
        int oo = t >> 6;
        int c  = IN_F + (t & 63);
        float v = (c == IN_F) ? bias[o0 + oo] : 0.0f;
        Bw[(size_t)(o0 + oo) * KP + c] = (bf16_t)v;
    }
}

// ---------------------------------------------------------------------------
// NT bf16 GEMM: C[8192x4096] = Aw[8192xKP] * Bw[4096xKP]^T  (fp32 out)
// m97 structure: 128x128 block tile, BK=64, 4 waves in 2x2, 4x4 MFMA tiles/wave.
#define BM 128
#define BN 128
#define BK 64

__global__ __launch_bounds__(256) void gemm_bt(const bf16_t* __restrict__ A,
                                               const bf16_t* __restrict__ B,
                                               float* __restrict__ C) {
    __shared__ bf16_t As[BM * BK];   // 16 KB
    __shared__ bf16_t Bs[BN * BK];   // 16 KB

    int bid = blockIdx.x;
    int bn  = bid & 31;              // 4096/128 = 32 col tiles
    int bm  = bid >> 5;              // 8192/128 = 64 row tiles
    int rowBase = bm * BM;
    int colBase = bn * BN;

    int t    = threadIdx.x;
    int lane = t & 63;
    int wave = t >> 6;
    int wr   = wave >> 1, wc = wave & 1;
    int quad = lane >> 4;
    int ln15 = lane & 15;

    f32x4 acc[4][4];
    for (int i = 0; i < 4; ++i)
        for (int j = 0; j < 4; ++j) acc[i][j] = (f32x4){0.f, 0.f, 0.f, 0.f};

    const int kIters = KP / BK;      // 65

    for (int kt = 0; kt < kIters; ++kt) {
        int k0 = kt * BK;
        // stage A-tile and B-tile (16 KB each) via async 16B/lane DMA
        for (int i = 0; i < 4; ++i) {
            int slot = i * 256 + t;
            int r  = slot >> 3;
            int k8 = (slot & 7) * 8;
            load16_lds(A + (size_t)(rowBase + r) * KP + k0 + k8, &As[slot * 8]);
            load16_lds(B + (size_t)(colBase + r) * KP + k0 + k8, &Bs[slot * 8]);
        }
        __syncthreads();             // compiler emits vmcnt(0) drain before barrier

        for (int kk = 0; kk < BK; kk += 32) {
            int kIn = kk + quad * 8;
            bf16x8 af[4], bfr[4];
            for (int mi = 0; mi < 4; ++mi) {
                int row = wr * 64 + mi * 16 + ln15;
                af[mi] = *(const bf16x8*)&As[row * BK + kIn];
            }
            for (int ni = 0; ni < 4; ++ni) {
                int col = wc * 64 + ni * 16 + ln15;
                bfr[ni] = *(const bf16x8*)&Bs[col * BK + kIn];
            }
            for (int mi = 0; mi < 4; ++mi)
                for (int ni = 0; ni < 4; ++ni)
                    acc[mi][ni] = __builtin_amdgcn_mfma_f32_16x16x32_bf16(
                        af[mi], bfr[ni], acc[mi][ni], 0, 0, 0);
        }
        __syncthreads();
    }

    // epilogue: pure store (bias already folded via K-pad column)
    for (int mi = 0; mi < 4; ++mi) {
        int row0 = rowBase + wr * 64 + mi * 16 + quad * 4;
        for (int ni = 0; ni < 4; ++ni) {
            int col = colBase + wc * 64 + ni * 16 + ln15;
            for (int reg = 0; reg < 4; ++reg)
                C[(size_t)(row0 + reg) * OUT_F + col] = acc[mi][ni][reg];
        }
    }
}

// ---------------------------------------------------------------------------
extern "C" void kernel_launch(void* const* d_in, const int* in_sizes, int n_in,
                              void* d_out, int out_size, void* d_ws, size_t ws_size,
                              hipStream_t stream) {
    const float* x  = (const float*)d_in[0];   // (8192, 4096)
    const float* W  = (const float*)d_in[1];   // (4096, 4096)
    const float* b  = (const float*)d_in[2];   // (4096,)
    const float* lA = (const float*)d_in[3];   // (16, 4096)
    const float* lB = (const float*)d_in[4];   // (4096, 16)
    float* out = (float*)d_out;                // (8192, 4096) fp32

    // workspace layout: Aw (8192 x 4160 bf16), Bw (4096 x 4160 bf16) ~102.3 MB
    bf16_t* Aw = (bf16_t*)d_ws;
    bf16_t* Bw = Aw + (size_t)N_ROWS * KP;

    prep_a<<<2048, 256, 0, stream>>>(x, Aw);
    prep_b<<<OUT_F / 4, 256, 0, stream>>>(W, b, lA, lB, Bw);
    gemm_bt<<<(N_ROWS / BM) * (OUT_F / BN), 256, 0, stream>>>(Aw, Bw, out);
}

// Round 2
// 625.415 us; speedup vs baseline: 1.1261x; 1.1261x over previous
//
#include <hip/hip_runtime.h>
#include <hip/hip_bf16.h>
#include <stdint.h>

// Problem constants
#define N_ROWS 8192
#define IN_F   4096
#define OUT_F  4096
#define R_LORA 16
#define KP     4160   // padded K: 4096 data + col 4096 = bias-1.0 trick + zeros to /64

typedef __bf16 bf16_t;
typedef __attribute__((ext_vector_type(8))) __bf16 bf16x8;
typedef __attribute__((ext_vector_type(4))) __bf16 bf16x4;
typedef __attribute__((ext_vector_type(4))) float  f32x4;

// ---------------------------------------------------------------------------
// async global->LDS, 16B per lane. LDS dest must be wave_base + lane*16.
// Per-lane SOURCE address is free-form (gather) — only the dest is constrained.
__device__ __forceinline__ void load16_lds(const bf16_t* g, bf16_t* l) {
    auto gp = (const __attribute__((address_space(1))) void*)g;
    auto lp = (__attribute__((address_space(3))) void*)(uint32_t)(uintptr_t)l;
    __builtin_amdgcn_global_load_lds(gp, lp, 16, 0, 0);
}

// ---------------------------------------------------------------------------
// prep_a: Aw[row][0:4096] = bf16(x), Aw[row][4096] = 1.0, rest of pad = 0.
// One block per row: pure stream, no integer division.
__global__ __launch_bounds__(256) void prep_a(const float* __restrict__ x,
                                              bf16_t* __restrict__ Aw) {
    int row = blockIdx.x;
    const float4* xr = (const float4*)(x + (size_t)row * IN_F);
    bf16_t* ar = Aw + (size_t)row * KP;
    int t = threadIdx.x;
    // 512 data slots of 8 bf16; 2 per thread
    for (int s = t; s < 512; s += 256) {
        float4 f0 = xr[2 * s];
        float4 f1 = xr[2 * s + 1];
        bf16x8 v;
        v[0] = (bf16_t)f0.x; v[1] = (bf16_t)f0.y;
        v[2] = (bf16_t)f0.z; v[3] = (bf16_t)f0.w;
        v[4] = (bf16_t)f1.x; v[5] = (bf16_t)f1.y;
        v[6] = (bf16_t)f1.z; v[7] = (bf16_t)f1.w;
        *(bf16x8*)(ar + s * 8) = v;
    }
    // pad: 64 cols, first is the bias-1.0 column
    if (t < 64) ar[IN_F + t] = (t == 0) ? (bf16_t)1.0f : (bf16_t)0.0f;
}

// ---------------------------------------------------------------------------
// prep_b: Bw[o][i] = bf16( W[o][i] + 2*sum_r lora_B[o][r]*lora_A[r][i] ),
//         Bw[o][4096] = bf16(b[o]), rest of pad = 0.
// One block handles 4 consecutive o rows (amortizes lora_A L2 reads 4x).
__global__ __launch_bounds__(256) void prep_b(const float* __restrict__ W,
                                              const float* __restrict__ bias,
                                              const float* __restrict__ lA,
                                              const float* __restrict__ lB,
                                              bf16_t* __restrict__ Bw) {
    int o0 = blockIdx.x * 4;
    int t  = threadIdx.x;

    float bl[4][R_LORA];
    for (int oo = 0; oo < 4; ++oo)
        for (int r = 0; r < R_LORA; ++r)
            bl[oo][r] = 2.0f * lB[(o0 + oo) * R_LORA + r];

    for (int j = 0; j < IN_F / (256 * 4); ++j) {   // 4 iterations
        int i4 = (j * 256 + t) * 4;
        f32x4 acc[4];
        for (int oo = 0; oo < 4; ++oo) {
            float4 w = *(const float4*)(W + (size_t)(o0 + oo) * IN_F + i4);
            acc[oo] = (f32x4){w.x, w.y, w.z, w.w};
        }
        for (int r = 0; r < R_LORA; ++r) {
            float4 a = *(const float4*)(lA + (size_t)r * IN_F + i4);
            for (int oo = 0; oo < 4; ++oo) {
                acc[oo][0] += bl[oo][r] * a.x;
                acc[oo][1] += bl[oo][r] * a.y;
                acc[oo][2] += bl[oo][r] * a.z;
                acc[oo][3] += bl[oo][r] * a.w;
            }
        }
        for (int oo = 0; oo < 4; ++oo) {
            bf16x4 v;
            v[0] = (bf16_t)acc[oo][0]; v[1] = (bf16_t)acc[oo][1];
            v[2] = (bf16_t)acc[oo][2]; v[3] = (bf16_t)acc[oo][3];
            *(bf16x4*)(Bw + (size_t)(o0 + oo) * KP + i4) = v;
        }
    }
    // pad columns: 4 rows x 64 cols = 256 slots, one per thread
    {
        int oo = t >> 6;
        int c  = IN_F + (t & 63);
        float v = (c == IN_F) ? bias[o0 + oo] : 0.0f;
        Bw[(size_t)(o0 + oo) * KP + c] = (bf16_t)v;
    }
}

// ---------------------------------------------------------------------------
// NT bf16 GEMM: C[8192x4096] = Aw[8192xKP] * Bw[4096xKP]^T  (fp32 out)
// 128x128 block tile, BK=64, 4 waves in 2x2, 4x4 MFMA tiles/wave.
// LDS layout is XOR-swizzled: chunk p (16B) of row r lives at slot position
// p ^ (r&7). Row stride 128 B == 0 mod banks, so without the swizzle a
// fragment read (fixed chunk, 16 rows) is a 16-way bank conflict; with it,
// the 8 pos-groups spread over all 32 banks -> b128 floor rate.
#define BM 128
#define BN 128
#define BK 64

__global__ __launch_bounds__(256) void gemm_bt(const bf16_t* __restrict__ A,
                                               const bf16_t* __restrict__ B,
                                               float* __restrict__ C) {
    __shared__ bf16_t As[BM * BK];   // 16 KB
    __shared__ bf16_t Bs[BN * BK];   // 16 KB

    int bid = blockIdx.x;
    int bn  = bid & 31;              // 4096/128 = 32 col tiles
    int bm  = bid >> 5;              // 8192/128 = 64 row tiles
    int rowBase = bm * BM;
    int colBase = bn * BN;

    int t    = threadIdx.x;
    int lane = t & 63;
    int wave = t >> 6;
    int wr   = wave >> 1, wc = wave & 1;
    int quad = lane >> 4;
    int ln15 = lane & 15;
    int l7   = ln15 & 7;

    f32x4 acc[4][4];
    for (int i = 0; i < 4; ++i)
        for (int j = 0; j < 4; ++j) acc[i][j] = (f32x4){0.f, 0.f, 0.f, 0.f};

    const int kIters = KP / BK;      // 65

    for (int kt = 0; kt < kIters; ++kt) {
        int k0 = kt * BK;
        // stage A-tile and B-tile (16 KB each) via async 16B/lane DMA.
        // LDS slot (r, p) receives global chunk (r, p ^ (r&7)). Global
        // coalescing unchanged: 8 lanes still cover each 128B row segment.
        for (int i = 0; i < 4; ++i) {
            int slot = i * 256 + t;
            int r  = slot >> 3;
            int p  = slot & 7;
            int srcOff = ((p ^ (r & 7)) * 8);
            load16_lds(A + (size_t)(rowBase + r) * KP + k0 + srcOff, &As[slot * 8]);
            load16_lds(B + (size_t)(colBase + r) * KP + k0 + srcOff, &Bs[slot * 8]);
        }
        __syncthreads();

        for (int kk = 0; kk < BK; kk += 32) {
            int cb = kk >> 3;                      // chunk base: 0 or 4
            int posOff = ((cb + quad) ^ l7) * 8;   // swizzled chunk position
            bf16x8 af[4], bfr[4];
            for (int mi = 0; mi < 4; ++mi) {
                int row = wr * 64 + mi * 16 + ln15;   // row&7 == l7
                af[mi] = *(const bf16x8*)&As[row * BK + posOff];
            }
            for (int ni = 0; ni < 4; ++ni) {
                int col = wc * 64 + ni * 16 + ln15;   // col&7 == l7
                bfr[ni] = *(const bf16x8*)&Bs[col * BK + posOff];
            }
            for (int mi = 0; mi < 4; ++mi)
                for (int ni = 0; ni < 4; ++ni)
                    acc[mi][ni] = __builtin_amdgcn_mfma_f32_16x16x32_bf16(
                        af[mi], bfr[ni], acc[mi][ni], 0, 0, 0);
        }
        __syncthreads();
    }

    // epilogue: pure store (bias already folded via K-pad column)
    for (int mi = 0; mi < 4; ++mi) {
        int row0 = rowBase + wr * 64 + mi * 16 + quad * 4;
        for (int ni = 0; ni < 4; ++ni) {
            int col = colBase + wc * 64 + ni * 16 + ln15;
            for (int reg = 0; reg < 4; ++reg)
                C[(size_t)(row0 + reg) * OUT_F + col] = acc[mi][ni][reg];
        }
    }
}

// ---------------------------------------------------------------------------
extern "C" void kernel_launch(void* const* d_in, const int* in_sizes, int n_in,
                              void* d_out, int out_size, void* d_ws, size_t ws_size,
                              hipStream_t stream) {
    const float* x  = (const float*)d_in[0];   // (8192, 4096)
    const float* W  = (const float*)d_in[1];   // (4096, 4096)
    const float* b  = (const float*)d_in[2];   // (4096,)
    const float* lA = (const float*)d_in[3];   // (16, 4096)
    const float* lB = (const float*)d_in[4];   // (4096, 16)
    float* out = (float*)d_out;                // (8192, 4096) fp32

    // workspace layout: Aw (8192 x 4160 bf16), Bw (4096 x 4160 bf16) ~102.3 MB
    bf16_t* Aw = (bf16_t*)d_ws;
    bf16_t* Bw = Aw + (size_t)N_ROWS * KP;

    prep_a<<<N_ROWS, 256, 0, stream>>>(x, Aw);
    prep_b<<<OUT_F / 4, 256, 0, stream>>>(W, b, lA, lB, Bw);
    gemm_bt<<<(N_ROWS / BM) * (OUT_F / BN), 256, 0, stream>>>(Aw, Bw, out);
}

// Round 3
// 557.747 us; speedup vs baseline: 1.2627x; 1.1213x over previous
//
#include <hip/hip_runtime.h>
#include <hip/hip_bf16.h>
#include <stdint.h>

// Problem constants
#define N_ROWS 8192
#define IN_F   4096
#define OUT_F  4096
#define R_LORA 16
#define KP     4160   // padded K: 4096 data + col 4096 = bias-1.0 trick + zeros to /64

typedef __bf16 bf16_t;
typedef __attribute__((ext_vector_type(8))) __bf16 bf16x8;
typedef __attribute__((ext_vector_type(4))) __bf16 bf16x4;
typedef __attribute__((ext_vector_type(4))) float  f32x4;
typedef __attribute__((ext_vector_type(16))) float f32x16;

// ---------------------------------------------------------------------------
// async global->LDS, 16B per lane. LDS dest must be wave_base + lane*16.
// Per-lane SOURCE address is free-form (gather) — only the dest is constrained.
__device__ __forceinline__ void load16_lds(const bf16_t* g, bf16_t* l) {
    auto gp = (const __attribute__((address_space(1))) void*)g;
    auto lp = (__attribute__((address_space(3))) void*)(uint32_t)(uintptr_t)l;
    __builtin_amdgcn_global_load_lds(gp, lp, 16, 0, 0);
}

// ---------------------------------------------------------------------------
// Fused prep: blocks [0,2048) build Aw (4 rows each); blocks [2048,3072)
// build Bw (4 o-rows each). One launch -> one drain, both streams concurrent.
#define PREPA_BLOCKS 2048

__global__ __launch_bounds__(256) void prep_fused(const float* __restrict__ x,
                                                  const float* __restrict__ W,
                                                  const float* __restrict__ bias,
                                                  const float* __restrict__ lA,
                                                  const float* __restrict__ lB,
                                                  bf16_t* __restrict__ Aw,
                                                  bf16_t* __restrict__ Bw) {
    int b = blockIdx.x;
    int t = threadIdx.x;
    if (b < PREPA_BLOCKS) {
        // ---- prep_a: Aw[row][0:4096]=bf16(x), col 4096 = 1.0, rest pad 0
        int row0 = b * 4;
        for (int rr = 0; rr < 4; ++rr) {
            int row = row0 + rr;
            const float4* xr = (const float4*)(x + (size_t)row * IN_F);
            bf16_t* ar = Aw + (size_t)row * KP;
            for (int s = t; s < 512; s += 256) {
                float4 f0 = xr[2 * s];
                float4 f1 = xr[2 * s + 1];
                bf16x8 v;
                v[0] = (bf16_t)f0.x; v[1] = (bf16_t)f0.y;
                v[2] = (bf16_t)f0.z; v[3] = (bf16_t)f0.w;
                v[4] = (bf16_t)f1.x; v[5] = (bf16_t)f1.y;
                v[6] = (bf16_t)f1.z; v[7] = (bf16_t)f1.w;
                *(bf16x8*)(ar + s * 8) = v;
            }
            if (t < 64) ar[IN_F + t] = (t == 0) ? (bf16_t)1.0f : (bf16_t)0.0f;
        }
    } else {
        // ---- prep_b: Bw[o][i] = bf16(W[o][i] + 2*sum_r lB[o][r]*lA[r][i]),
        //      Bw[o][4096] = b[o], rest pad 0.
        int o0 = (b - PREPA_BLOCKS) * 4;
        float bl[4][R_LORA];
        for (int oo = 0; oo < 4; ++oo)
            for (int r = 0; r < R_LORA; ++r)
                bl[oo][r] = 2.0f * lB[(o0 + oo) * R_LORA + r];

        for (int j = 0; j < IN_F / (256 * 4); ++j) {   // 4 iterations
            int i4 = (j * 256 + t) * 4;
            f32x4 acc[4];
            for (int oo = 0; oo < 4; ++oo) {
                float4 w = *(const float4*)(W + (size_t)(o0 + oo) * IN_F + i4);
                acc[oo] = (f32x4){w.x, w.y, w.z, w.w};
            }
            for (int r = 0; r < R_LORA; ++r) {
                float4 a = *(const float4*)(lA + (size_t)r * IN_F + i4);
                for (int oo = 0; oo < 4; ++oo) {
                    acc[oo][0] += bl[oo][r] * a.x;
                    acc[oo][1] += bl[oo][r] * a.y;
                    acc[oo][2] += bl[oo][r] * a.z;
                    acc[oo][3] += bl[oo][r] * a.w;
                }
            }
            for (int oo = 0; oo < 4; ++oo) {
                bf16x4 v;
                v[0] = (bf16_t)acc[oo][0]; v[1] = (bf16_t)acc[oo][1];
                v[2] = (bf16_t)acc[oo][2]; v[3] = (bf16_t)acc[oo][3];
                *(bf16x4*)(Bw + (size_t)(o0 + oo) * KP + i4) = v;
            }
        }
        {   // pad columns: 4 rows x 64 cols = 256 slots, one per thread
            int oo = t >> 6;
            int c  = IN_F + (t & 63);
            float v = (c == IN_F) ? bias[o0 + oo] : 0.0f;
            Bw[(size_t)(o0 + oo) * KP + c] = (bf16_t)v;
        }
    }
}

// ---------------------------------------------------------------------------
// NT bf16 GEMM: C[8192x4096] = Aw[8192xKP] * Bw[4096xKP]^T  (fp32 out)
// 128x128 block tile, BK=64, 4 waves in 2x2; each wave = 2x2 tiles of
// 32x32x16 MFMA (halves MFMA+ds_read issue slots vs 16x16x32).
// LDS XOR swizzle: 16B chunk p of row r lives at position p ^ (r&7)
// (row stride 128 B == 0 mod banks; swizzle makes fragment reads
// conflict-free — measured 0 SQ_LDS_BANK_CONFLICT).
#define BM 128
#define BN 128
#define BK 64

__global__ __launch_bounds__(256) void gemm_bt(const bf16_t* __restrict__ A,
                                               const bf16_t* __restrict__ B,
                                               float* __restrict__ C) {
    __shared__ bf16_t As[BM * BK];   // 16 KB
    __shared__ bf16_t Bs[BN * BK];   // 16 KB

    int bid = blockIdx.x;
    int bn  = bid & 31;              // 4096/128 = 32 col tiles
    int bm  = bid >> 5;              // 8192/128 = 64 row tiles
    int rowBase = bm * BM;
    int colBase = bn * BN;

    int t    = threadIdx.x;
    int lane = t & 63;
    int wave = t >> 6;
    int wr   = wave >> 1, wc = wave & 1;
    int l31  = lane & 31;
    int lhi  = lane >> 5;            // 0/1: which K-half of the fragment
    int l7   = lane & 7;

    f32x16 acc[2][2];
    for (int i = 0; i < 2; ++i)
        for (int j = 0; j < 2; ++j)
            for (int r = 0; r < 16; ++r) acc[i][j][r] = 0.f;

    const int kIters = KP / BK;      // 65

    for (int kt = 0; kt < kIters; ++kt) {
        int k0 = kt * BK;
        // stage A-tile and B-tile (16 KB each) via async 16B/lane DMA.
        // LDS slot (r,p) receives global chunk (r, p ^ (r&7)).
        for (int i = 0; i < 4; ++i) {
            int slot = i * 256 + t;
            int r  = slot >> 3;
            int p  = slot & 7;
            int srcOff = ((p ^ (r & 7)) * 8);
            load16_lds(A + (size_t)(rowBase + r) * KP + k0 + srcOff, &As[slot * 8]);
            load16_lds(B + (size_t)(colBase + r) * KP + k0 + srcOff, &Bs[slot * 8]);
        }
        __syncthreads();

        // 4 K-steps of 16; A/B fragment: lane holds [l31][8*lhi + j] (8 contig)
        for (int ks = 0; ks < 4; ++ks) {
            int chunk = (ks << 1) + lhi;
            int posOff = (chunk ^ l7) * 8;       // swizzled 8-elem position
            bf16x8 af[2], bfg[2];
            for (int ti = 0; ti < 2; ++ti) {
                int row = wr * 64 + ti * 32 + l31;    // row&7 == l7
                af[ti] = *(const bf16x8*)&As[row * BK + posOff];
            }
            for (int tj = 0; tj < 2; ++tj) {
                int col = wc * 64 + tj * 32 + l31;    // col&7 == l7
                bfg[tj] = *(const bf16x8*)&Bs[col * BK + posOff];
            }
            for (int ti = 0; ti < 2; ++ti)
                for (int tj = 0; tj < 2; ++tj)
                    acc[ti][tj] = __builtin_amdgcn_mfma_f32_32x32x16_bf16(
                        af[ti], bfg[tj], acc[ti][tj], 0, 0, 0);
        }
        __syncthreads();
    }

    // epilogue: C/D layout col=l&31, row=(reg&3)+8*(reg>>2)+4*(l>>5)
    for (int ti = 0; ti < 2; ++ti) {
        int rB = rowBase + wr * 64 + ti * 32 + 4 * lhi;
        for (int tj = 0; tj < 2; ++tj) {
            int col = colBase + wc * 64 + tj * 32 + l31;
            for (int reg = 0; reg < 16; ++reg) {
                int row = rB + (reg & 3) + 8 * (reg >> 2);
                C[(size_t)row * OUT_F + col] = acc[ti][tj][reg];
            }
        }
    }
}

// ---------------------------------------------------------------------------
extern "C" void kernel_launch(void* const* d_in, const int* in_sizes, int n_in,
                              void* d_out, int out_size, void* d_ws, size_t ws_size,
                              hipStream_t stream) {
    const float* x  = (const float*)d_in[0];   // (8192, 4096)
    const float* W  = (const float*)d_in[1];   // (4096, 4096)
    const float* b  = (const float*)d_in[2];   // (4096,)
    const float* lA = (const float*)d_in[3];   // (16, 4096)
    const float* lB = (const float*)d_in[4];   // (4096, 16)
    float* out = (float*)d_out;                // (8192, 4096) fp32

    // workspace layout: Aw (8192 x 4160 bf16), Bw (4096 x 4160 bf16) ~102.3 MB
    bf16_t* Aw = (bf16_t*)d_ws;
    bf16_t* Bw = Aw + (size_t)N_ROWS * KP;

    prep_fused<<<PREPA_BLOCKS + OUT_F / 4, 256, 0, stream>>>(x, W, b, lA, lB, Aw, Bw);
    gemm_bt<<<(N_ROWS / BM) * (OUT_F / BN), 256, 0, stream>>>(Aw, Bw, out);
}